// Round 11
// baseline (885.206 us; speedup 1.0000x reference)
//
#include <hip/hip_runtime.h>
#include <hip/hip_cooperative_groups.h>

namespace cg = cooperative_groups;

// ---------- types ----------
typedef __bf16 bf16x8 __attribute__((ext_vector_type(8)));
typedef float  floatx4 __attribute__((ext_vector_type(4)));
typedef unsigned short ushortx8 __attribute__((ext_vector_type(8)));
typedef unsigned short ushortx4 __attribute__((ext_vector_type(4)));
typedef unsigned short ushortx2 __attribute__((ext_vector_type(2)));

__device__ __forceinline__ float bf2f(unsigned short u) {
    return __uint_as_float(((unsigned)u) << 16);
}
__device__ __forceinline__ unsigned short f2bf(float f) {
    unsigned u = __float_as_uint(f);
    return (unsigned short)((u + 0x7FFFu + ((u >> 16) & 1u)) >> 16);
}

// async global->LDS, 16B per lane; lds dest = wave-uniform base + lane*16.
// NOTE (r6): NEVER use the builtin's imm-offset field (NaN — offset applies to
// the LDS side). All offsets in the global ADDRESS; offset arg always 0.
__device__ __forceinline__ void gload_lds16(const unsigned short* g, unsigned short* l) {
    __builtin_amdgcn_global_load_lds(
        (const __attribute__((address_space(1))) void*)g,
        (__attribute__((address_space(3))) void*)l, 16, 0, 0);
}

// ============================================================================
// STAGED (fragment-order) GLOBAL LAYOUT (r7): A/B pre-packed in the exact
// per-(row-tile,K-step) LDS image so GEMM staging reads are 1KB contiguous.
//   elem = ((tile*8+kti)<<13) + ((s*8+g)<<9) + ((q*16+mrow)<<3) + (k&7)
// ============================================================================
#define NKT 8   // K=512 -> 8 K-steps of 64

__device__ __forceinline__ size_t staged_chunk(int r, int c /*k>>3*/) {
    int tile = r >> 7, rt = r & 127;
    int g = rt >> 4, mrow = rt & 15;
    int kti = c >> 3, c7 = c & 7;
    int s = c7 >> 2, q = c7 & 3;
    return (((size_t)tile * NKT + kti) << 13) + ((size_t)(s * 8 + g) << 9)
         + ((size_t)((q << 4) | mrow) << 3);
}

// ---------- fused prep: cvt x, transpose W1/W2, init head (1 launch) ----------
__global__ __launch_bounds__(256) void prep_kernel(
    const float* __restrict__ x,  unsigned short* __restrict__ xb,  int nchunk, int bc,
    const float* __restrict__ W1, unsigned short* __restrict__ W1t, int bw1,
    const float* __restrict__ W2, unsigned short* __restrict__ W2t, int bw2,
    int* __restrict__ head, int nhead, int FIN, int FOUT)
{
    const int bid = blockIdx.x, tid = threadIdx.x;
    if (bid < bc) {
        int i = bid * 256 + tid;
        if (i < nchunk) {
            int r = i >> 6, c = i & 63;
            float4 v0 = ((const float4*)x)[i * 2];
            float4 v1 = ((const float4*)x)[i * 2 + 1];
            ushortx8 o;
            o[0] = f2bf(v0.x); o[1] = f2bf(v0.y); o[2] = f2bf(v0.z); o[3] = f2bf(v0.w);
            o[4] = f2bf(v1.x); o[5] = f2bf(v1.y); o[6] = f2bf(v1.z); o[7] = f2bf(v1.w);
            *(ushortx8*)(xb + staged_chunk(r, c)) = o;
        }
    } else if (bid < bc + bw1) {
        int idx = (bid - bc) * 256 + tid;
        if (idx < FIN * FIN) {
            int k = idx / FIN, n = idx - k * FIN;
            W1t[staged_chunk(n, k >> 3) + (k & 7)] = f2bf(W1[idx]);
        }
    } else if (bid < bc + bw1 + bw2) {
        int idx = (bid - bc - bw1) * 256 + tid;
        if (idx < FIN * FOUT) {
            int k = idx / FOUT, n = idx - k * FOUT;
            W2t[staged_chunk(n, k >> 3) + (k & 7)] = f2bf(W2[idx]);
        }
    } else {
        int i = (bid - bc - bw1 - bw2) * 256 + tid;
        if (i < nhead) head[i] = -1;
    }
}

// two lists per dst: head[mask*Nn + dst]
__global__ void build_list_kernel(const int* __restrict__ ei, const int* __restrict__ em,
                                  int E, int Nn,
                                  int* __restrict__ head, int* __restrict__ nxt) {
    int e = blockIdx.x * blockDim.x + threadIdx.x;
    if (e >= E) return;
    int d = ei[E + e];
    int m = em[e];
    nxt[e] = atomicExch(&head[m * Nn + d], e);
}

// ---------- GEMM: C[M,N] = A@B + bias; A,Bt in STAGED layout; C linear ------
#define BM 128
#define BN 128

__global__ __launch_bounds__(256, 4) void gemm_bt_bias(
    const unsigned short* __restrict__ A,    // staged [tiles][NKT][16KB]
    const unsigned short* __restrict__ Bt,   // staged
    const float* __restrict__ bias,          // N (fp32)
    unsigned short* __restrict__ C,          // M x N  (bf16 bits), linear
    int M, int N, int K)
{
    __shared__ unsigned short Sh[16384];     // 32 KB
    unsigned short (*As)[512] = (unsigned short(*)[512])Sh;
    unsigned short (*Bs)[512] = (unsigned short(*)[512])(Sh + 8192);

    const int tid  = threadIdx.x;
    const int lane = tid & 63;
    const int wave = tid >> 6;

    int bx, by;
    if (gridDim.x == 4) {
        int id = blockIdx.y * 4 + blockIdx.x;
        int full = (gridDim.y & ~7) * 4;
        if (id < full) {
            bx = (id >> 3) & 3;
            by = (id >> 5) * 8 + (id & 7);
        } else {
            int t = id - full;
            by = (gridDim.y & ~7) + (t >> 2);
            bx = t & 3;
        }
    } else {
        bx = blockIdx.x; by = blockIdx.y;
    }
    const int bM = by * BM;
    const int bN = bx * BN;
    const int wm = (wave >> 1) * 64;
    const int wn = (wave & 1) * 64;
    const int q    = lane >> 4;
    const int mrow = lane & 15;

    const unsigned short* as_ = A  + (((size_t)by * NKT) << 13) + (wave << 11) + (lane << 3);
    const unsigned short* bs_ = Bt + (((size_t)bx * NKT) << 13) + (wave << 11) + (lane << 3);

    floatx4 acc[4][4];
#pragma unroll
    for (int i = 0; i < 4; i++)
#pragma unroll
        for (int j = 0; j < 4; j++) acc[i][j] = (floatx4)(0.0f);

    for (int t = 0; t < NKT; ++t) {
#pragma unroll
        for (int c = 0; c < 4; c++) {
            gload_lds16(as_ + (c << 9), Sh + (wave << 11) + (c << 9));
            gload_lds16(bs_ + (c << 9), Sh + 8192 + (wave << 11) + (c << 9));
        }
        __syncthreads();

#pragma unroll
        for (int s = 0; s < 2; s++) {
            bf16x8 af[4], bfv[4];
#pragma unroll
            for (int mi = 0; mi < 4; mi++)
                af[mi] = *(const bf16x8*)&As[s * 8 + (wave >> 1) * 4 + mi][lane * 8];
#pragma unroll
            for (int ni = 0; ni < 4; ni++)
                bfv[ni] = *(const bf16x8*)&Bs[s * 8 + (wave & 1) * 4 + ni][lane * 8];
#pragma unroll
            for (int mi = 0; mi < 4; mi++)
#pragma unroll
                for (int ni = 0; ni < 4; ni++)
                    acc[mi][ni] = __builtin_amdgcn_mfma_f32_16x16x32_bf16(
                        af[mi], bfv[ni], acc[mi][ni], 0, 0, 0);
        }
        __syncthreads();
        as_ += 8192; bs_ += 8192;
    }

    unsigned short* lbuf = Sh + wave * 2048;
    float bv[4];
#pragma unroll
    for (int ni = 0; ni < 4; ni++) bv[ni] = bias[bN + wn + ni * 16 + mrow];

#pragma unroll
    for (int p = 0; p < 2; p++) {
#pragma unroll
        for (int mh = 0; mh < 2; mh++) {
            int mi = 2 * p + mh;
#pragma unroll
            for (int ni = 0; ni < 4; ni++)
#pragma unroll
                for (int r = 0; r < 4; r++)
                    lbuf[(mh * 16 + q * 4 + r) * 64 + ni * 16 + mrow] =
                        f2bf(acc[mi][ni][r] + bv[ni]);
        }
#pragma unroll
        for (int i = 0; i < 4; i++) {
            int prow = i * 8 + (lane >> 3);
            int pcol = (lane & 7) * 8;
            int grow = bM + wm + p * 32 + prow;
            if (grow < M)
                *(ushortx8*)(C + (size_t)grow * N + bN + wn + pcol) =
                    *(const ushortx8*)&lbuf[prow * 64 + pcol];
        }
    }
}

// ---------- fused propagate pair (cooperative): S0 then grid-sync then S1 ----
// r11: fuses prop pairs (4 launches -> 2) AND finally makes the prop visible
// in rocprof top-5 (the ~73us harness fills hid every individual prop; the
// fused kernel should exceed them). Grid = 2048 blocks exactly co-resident
// (8 blk/CU x 256 CU, LDS=0, VGPR<=64 via launch_bounds). grid.sync() gives
// device-scope visibility of phase-A writes (cross-XCD safe per guide G16).
template <int VEC> struct VecT;
template <> struct VecT<8> { typedef ushortx8 type; };
template <> struct VecT<2> { typedef ushortx2 type; };

template <int VEC, bool RELU, bool OUT_F32, bool OUT_STAGED>
__global__ __launch_bounds__(256, 8) void prop_fused_kernel(
    const unsigned short* __restrict__ cur,  // input features [Nn,F] bf16 linear
    unsigned short* __restrict__ mid,        // S0 result (linear bf16)
    void* __restrict__ outp,                 // final out: bf16 staged / linear / fp32
    const int* __restrict__ head,            // [2*Nn] mask0 then mask1
    const int* __restrict__ nxt,
    const int* __restrict__ esrc,
    int Nn)
{
    typedef typename VecT<VEC>::type VT;
    const int lane = threadIdx.x & 63;
    const int F = VEC * 64;
    const int wstart = blockIdx.x * 4 + (threadIdx.x >> 6);
    const int wstep  = gridDim.x * 4;

    // ---- phase A: mid = S0(cur) ----
    for (int w = wstart; w < Nn; w += wstep) {
        float acc[VEC];
#pragma unroll
        for (int i = 0; i < VEC; i++) acc[i] = 0.0f;
        for (int e = head[w]; e >= 0; e = nxt[e]) {
            int s = esrc[e];
            VT v = *(const VT*)(cur + (size_t)s * F + lane * VEC);
#pragma unroll
            for (int i = 0; i < VEC; i++) acc[i] += bf2f(v[i]);
        }
        VT o;
#pragma unroll
        for (int i = 0; i < VEC; i++) o[i] = f2bf(acc[i]);
        *(VT*)(mid + (size_t)w * F + lane * VEC) = o;
    }

    cg::this_grid().sync();   // all S0 writes visible device-wide

    // ---- phase B: out = [relu](mid + S1(mid)) ----
    for (int w = wstart; w < Nn; w += wstep) {
        const size_t off = (size_t)w * F + lane * VEC;
        VT sv = *(const VT*)(mid + off);
        float acc[VEC];
#pragma unroll
        for (int i = 0; i < VEC; i++) acc[i] = bf2f(sv[i]);
        for (int e = head[Nn + w]; e >= 0; e = nxt[e]) {
            int s = esrc[e];
            VT v = *(const VT*)(mid + (size_t)s * F + lane * VEC);
#pragma unroll
            for (int i = 0; i < VEC; i++) acc[i] += bf2f(v[i]);
        }
#pragma unroll
        for (int i = 0; i < VEC; i++)
            if (RELU && acc[i] < 0.0f) acc[i] = 0.0f;

        if (OUT_F32) {
            float* out = (float*)outp;
            float2 o2;
#pragma unroll
            for (int i = 0; i < VEC; i += 2) {
                o2.x = acc[i]; o2.y = acc[i + 1];
                *(float2*)(out + off + i) = o2;
            }
        } else {
            VT o;
#pragma unroll
            for (int i = 0; i < VEC; i++) o[i] = f2bf(acc[i]);
            if (OUT_STAGED && VEC == 8) {
                *(VT*)((unsigned short*)outp + staged_chunk(w, lane)) = o;
            } else {
                *(VT*)((unsigned short*)outp + off) = o;
            }
        }
    }
}

// ---------- launch ----------
extern "C" void kernel_launch(void* const* d_in, const int* in_sizes, int n_in,
                              void* d_out, int out_size, void* d_ws, size_t ws_size,
                              hipStream_t stream)
{
    const float* x  = (const float*)d_in[0];       // [Nn, 512] fp32
    const int*   ei = (const int*)d_in[1];         // [2, E] int32
    const int*   em = (const int*)d_in[2];         // [E]
    const float* W1 = (const float*)d_in[5];       // [512,512]
    const float* b1 = (const float*)d_in[6];       // [512]
    const float* W2 = (const float*)d_in[7];       // [512,128]
    const float* b2 = (const float*)d_in[8];       // [128]

    const int FIN = 512, FOUT = 128;
    const int Nn = in_sizes[0] / FIN;   // 60000
    const int E  = in_sizes[2];         // 160000
    const int Mpad = ((Nn + 127) >> 7) << 7;   // 60032

    char* ws = (char*)d_ws;
    size_t off = 0;
    auto alloc = [&](size_t bytes) -> char* {
        char* p = ws + off;
        off += (bytes + 255) & ~(size_t)255;
        return p;
    };
    unsigned short* W1t = (unsigned short*)alloc((size_t)FIN * FIN * 2);   // staged
    unsigned short* W2t = (unsigned short*)alloc((size_t)FIN * FOUT * 2);  // staged
    unsigned short* xb  = (unsigned short*)alloc((size_t)Mpad * FIN * 2);  // staged x; reused as A1 (linear)
    unsigned short* h1  = (unsigned short*)alloc((size_t)Mpad * FIN * 2);  // GEMM1 out (linear) -> B1 staged
    unsigned short* h2  = (unsigned short*)alloc((size_t)Nn * FOUT * 2);
    unsigned short* A2  = (unsigned short*)alloc((size_t)Nn * FOUT * 2);
    int* head = (int*)alloc((size_t)2 * Nn * 4);   // [2][Nn]
    int* nxt  = (int*)alloc((size_t)E * 4);
    unsigned short* A1 = xb;
    (void)ws_size; (void)n_in; (void)out_size;

    // 1) fused prep (1 launch)
    {
        int nchunk = Nn * (FIN / 8);
        int bc  = (nchunk + 255) / 256;
        int bw1 = (FIN * FIN + 255) / 256;
        int bw2 = (FIN * FOUT + 255) / 256;
        int bh  = (2 * Nn + 255) / 256;
        prep_kernel<<<bc + bw1 + bw2 + bh, 256, 0, stream>>>(
            x, xb, nchunk, bc, W1, W1t, bw1, W2, W2t, bw2, head, 2 * Nn, FIN, FOUT);
    }

    // 2) per-(mask,dst) linked lists
    build_list_kernel<<<(E + 255) / 256, 256, 0, stream>>>(ei, em, E, Nn, head, nxt);

    // 3) h1 = x @ W1 + b1   (staged A/B)
    {
        dim3 grid(FIN / BN, Mpad / BM);
        gemm_bt_bias<<<grid, 256, 0, stream>>>(xb, W1t, b1, h1, Nn, FIN, FIN);
    }

    // 4) P1 fused (cooperative): A1 = S0(h1); sync; h1 = staged(relu(A1 + S1(A1)))
    {
        const unsigned short* cur = h1;
        unsigned short* mid = A1;
        void* outp = (void*)h1;
        const int* hd = head;
        const int* nx = nxt;
        const int* es = ei;
        int nn = Nn;
        void* args[] = {(void*)&cur, (void*)&mid, (void*)&outp,
                        (void*)&hd, (void*)&nx, (void*)&es, (void*)&nn};
        hipLaunchCooperativeKernel(
            (const void*)&prop_fused_kernel<8, true, false, true>,
            dim3(2048), dim3(256), args, 0, stream);
    }

    // 5) h2 = B1 @ W2 + b2   (staged A/B)
    {
        dim3 grid(FOUT / BN, Mpad / BM);
        gemm_bt_bias<<<grid, 256, 0, stream>>>(h1, W2t, b2, h2, Nn, FOUT, FIN);
    }

    // 6) P2 fused (cooperative): A2 = S0(h2); sync; out = A2 + S1(A2)  (fp32)
    {
        const unsigned short* cur = h2;
        unsigned short* mid = A2;
        void* outp = d_out;
        const int* hd = head;
        const int* nx = nxt;
        const int* es = ei;
        int nn = Nn;
        void* args[] = {(void*)&cur, (void*)&mid, (void*)&outp,
                        (void*)&hd, (void*)&nx, (void*)&es, (void*)&nn};
        hipLaunchCooperativeKernel(
            (const void*)&prop_fused_kernel<2, false, true, false>,
            dim3(2048), dim3(256), args, 0, stream);
    }
}

// Round 12
// 373.344 us; speedup vs baseline: 2.3710x; 2.3710x over previous
//
#include <hip/hip_runtime.h>

// ---------- types ----------
typedef __bf16 bf16x8 __attribute__((ext_vector_type(8)));
typedef float  floatx4 __attribute__((ext_vector_type(4)));
typedef unsigned short ushortx8 __attribute__((ext_vector_type(8)));
typedef unsigned short ushortx4 __attribute__((ext_vector_type(4)));
typedef unsigned short ushortx2 __attribute__((ext_vector_type(2)));

__device__ __forceinline__ float bf2f(unsigned short u) {
    return __uint_as_float(((unsigned)u) << 16);
}
__device__ __forceinline__ unsigned short f2bf(float f) {
    unsigned u = __float_as_uint(f);
    return (unsigned short)((u + 0x7FFFu + ((u >> 16) & 1u)) >> 16);
}

// async global->LDS, 16B per lane; lds dest = wave-uniform base + lane*16.
// NOTE (r6): NEVER use the builtin's imm-offset field (NaN — offset applies to
// the LDS side). All offsets in the global ADDRESS; offset arg always 0.
__device__ __forceinline__ void gload_lds16(const unsigned short* g, unsigned short* l) {
    __builtin_amdgcn_global_load_lds(
        (const __attribute__((address_space(1))) void*)g,
        (__attribute__((address_space(3))) void*)l, 16, 0, 0);
}

// ============================================================================
// STAGED (fragment-order) GLOBAL LAYOUT (r7): A/B pre-packed in the exact
// per-(row-tile,K-step) LDS image so GEMM staging reads are 1KB contiguous.
//   elem = ((tile*8+kti)<<13) + ((s*8+g)<<9) + ((q*16+mrow)<<3) + (k&7)
// ============================================================================
#define NKT 8   // K=512 -> 8 K-steps of 64

__device__ __forceinline__ size_t staged_chunk(int r, int c /*k>>3*/) {
    int tile = r >> 7, rt = r & 127;
    int g = rt >> 4, mrow = rt & 15;
    int kti = c >> 3, c7 = c & 7;
    int s = c7 >> 2, q = c7 & 3;
    return (((size_t)tile * NKT + kti) << 13) + ((size_t)(s * 8 + g) << 9)
         + ((size_t)((q << 4) | mrow) << 3);
}

// ---------- fused prep: cvt x, transpose W1/W2, init head (1 launch) ----------
__global__ __launch_bounds__(256) void prep_kernel(
    const float* __restrict__ x,  unsigned short* __restrict__ xb,  int nchunk, int bc,
    const float* __restrict__ W1, unsigned short* __restrict__ W1t, int bw1,
    const float* __restrict__ W2, unsigned short* __restrict__ W2t, int bw2,
    int* __restrict__ head, int nhead, int FIN, int FOUT)
{
    const int bid = blockIdx.x, tid = threadIdx.x;
    if (bid < bc) {
        int i = bid * 256 + tid;
        if (i < nchunk) {
            int r = i >> 6, c = i & 63;
            float4 v0 = ((const float4*)x)[i * 2];
            float4 v1 = ((const float4*)x)[i * 2 + 1];
            ushortx8 o;
            o[0] = f2bf(v0.x); o[1] = f2bf(v0.y); o[2] = f2bf(v0.z); o[3] = f2bf(v0.w);
            o[4] = f2bf(v1.x); o[5] = f2bf(v1.y); o[6] = f2bf(v1.z); o[7] = f2bf(v1.w);
            *(ushortx8*)(xb + staged_chunk(r, c)) = o;
        }
    } else if (bid < bc + bw1) {
        int idx = (bid - bc) * 256 + tid;
        if (idx < FIN * FIN) {
            int k = idx / FIN, n = idx - k * FIN;
            W1t[staged_chunk(n, k >> 3) + (k & 7)] = f2bf(W1[idx]);
        }
    } else if (bid < bc + bw1 + bw2) {
        int idx = (bid - bc - bw1) * 256 + tid;
        if (idx < FIN * FOUT) {
            int k = idx / FOUT, n = idx - k * FOUT;
            W2t[staged_chunk(n, k >> 3) + (k & 7)] = f2bf(W2[idx]);
        }
    } else {
        int i = (bid - bc - bw1 - bw2) * 256 + tid;
        if (i < nhead) head[i] = -1;
    }
}

// two lists per dst: head[mask*Nn + dst]
__global__ void build_list_kernel(const int* __restrict__ ei, const int* __restrict__ em,
                                  int E, int Nn,
                                  int* __restrict__ head, int* __restrict__ nxt) {
    int e = blockIdx.x * blockDim.x + threadIdx.x;
    if (e >= E) return;
    int d = ei[E + e];
    int m = em[e];
    nxt[e] = atomicExch(&head[m * Nn + d], e);
}

// ---------- GEMM: C[M,N] = A@B + bias; A,Bt in STAGED layout; C linear ------
#define BM 128
#define BN 128

__global__ __launch_bounds__(256, 4) void gemm_bt_bias(
    const unsigned short* __restrict__ A,    // staged [tiles][NKT][16KB]
    const unsigned short* __restrict__ Bt,   // staged
    const float* __restrict__ bias,          // N (fp32)
    unsigned short* __restrict__ C,          // M x N  (bf16 bits), linear
    int M, int N, int K)
{
    __shared__ unsigned short Sh[16384];     // 32 KB
    unsigned short (*As)[512] = (unsigned short(*)[512])Sh;
    unsigned short (*Bs)[512] = (unsigned short(*)[512])(Sh + 8192);

    const int tid  = threadIdx.x;
    const int lane = tid & 63;
    const int wave = tid >> 6;

    int bx, by;
    if (gridDim.x == 4) {
        int id = blockIdx.y * 4 + blockIdx.x;
        int full = (gridDim.y & ~7) * 4;
        if (id < full) {
            bx = (id >> 3) & 3;
            by = (id >> 5) * 8 + (id & 7);
        } else {
            int t = id - full;
            by = (gridDim.y & ~7) + (t >> 2);
            bx = t & 3;
        }
    } else {
        bx = blockIdx.x; by = blockIdx.y;
    }
    const int bM = by * BM;
    const int bN = bx * BN;
    const int wm = (wave >> 1) * 64;
    const int wn = (wave & 1) * 64;
    const int q    = lane >> 4;
    const int mrow = lane & 15;

    const unsigned short* as_ = A  + (((size_t)by * NKT) << 13) + (wave << 11) + (lane << 3);
    const unsigned short* bs_ = Bt + (((size_t)bx * NKT) << 13) + (wave << 11) + (lane << 3);

    floatx4 acc[4][4];
#pragma unroll
    for (int i = 0; i < 4; i++)
#pragma unroll
        for (int j = 0; j < 4; j++) acc[i][j] = (floatx4)(0.0f);

    for (int t = 0; t < NKT; ++t) {
#pragma unroll
        for (int c = 0; c < 4; c++) {
            gload_lds16(as_ + (c << 9), Sh + (wave << 11) + (c << 9));
            gload_lds16(bs_ + (c << 9), Sh + 8192 + (wave << 11) + (c << 9));
        }
        __syncthreads();

#pragma unroll
        for (int s = 0; s < 2; s++) {
            bf16x8 af[4], bfv[4];
#pragma unroll
            for (int mi = 0; mi < 4; mi++)
                af[mi] = *(const bf16x8*)&As[s * 8 + (wave >> 1) * 4 + mi][lane * 8];
#pragma unroll
            for (int ni = 0; ni < 4; ni++)
                bfv[ni] = *(const bf16x8*)&Bs[s * 8 + (wave & 1) * 4 + ni][lane * 8];
#pragma unroll
            for (int mi = 0; mi < 4; mi++)
#pragma unroll
                for (int ni = 0; ni < 4; ni++)
                    acc[mi][ni] = __builtin_amdgcn_mfma_f32_16x16x32_bf16(
                        af[mi], bfv[ni], acc[mi][ni], 0, 0, 0);
        }
        __syncthreads();
        as_ += 8192; bs_ += 8192;
    }

    unsigned short* lbuf = Sh + wave * 2048;
    float bv[4];
#pragma unroll
    for (int ni = 0; ni < 4; ni++) bv[ni] = bias[bN + wn + ni * 16 + mrow];

#pragma unroll
    for (int p = 0; p < 2; p++) {
#pragma unroll
        for (int mh = 0; mh < 2; mh++) {
            int mi = 2 * p + mh;
#pragma unroll
            for (int ni = 0; ni < 4; ni++)
#pragma unroll
                for (int r = 0; r < 4; r++)
                    lbuf[(mh * 16 + q * 4 + r) * 64 + ni * 16 + mrow] =
                        f2bf(acc[mi][ni][r] + bv[ni]);
        }
#pragma unroll
        for (int i = 0; i < 4; i++) {
            int prow = i * 8 + (lane >> 3);
            int pcol = (lane & 7) * 8;
            int grow = bM + wm + p * 32 + prow;
            if (grow < M)
                *(ushortx8*)(C + (size_t)grow * N + bN + wn + pcol) =
                    *(const ushortx8*)&lbuf[prow * 64 + pcol];
        }
    }
}

// ---------- propagate step: TWO nodes per wave (r12 MLP doubling) ----------
// r11 evidence: props = ~235us (61% of total); phase counters occupancy 91%,
// VALU 5%, HBM 12% -> memory-parallelism-limited (1 dependent gather chain in
// flight per wave). Fix: wave j handles nodes 2j,2j+1 with the two edge
// chains interleaved -> 2 outstanding 1KB gathers per wave, 16384 chains
// chip-wide. Writes stay coalesced (2 adjacent rows per wave).
// Cooperative fusion (r11) REVERTED: grid.sync forces cross-XCD L2
// invalidation -> 1.75x slower per phase.
template <int VEC> struct VecT;
template <> struct VecT<8> { typedef ushortx8 type; };
template <> struct VecT<2> { typedef ushortx2 type; };

template <int VEC, bool ADD_SELF, bool RELU, bool OUT_F32, bool OUT_STAGED = false>
__global__ __launch_bounds__(256, 8) void prop_step_kernel(
    const unsigned short* __restrict__ cur,  // bf16 [Nn, F] linear
    void* __restrict__ outp,                 // bf16/fp32 linear, or staged bf16
    const int* __restrict__ head,            // per-mask list heads (pre-offset)
    const int* __restrict__ nxt,
    const int* __restrict__ esrc,
    int Nn)
{
    typedef typename VecT<VEC>::type VT;
    const int j = blockIdx.x * 4 + (threadIdx.x >> 6);   // wave id = node pair
    const int w0 = j * 2, w1 = w0 + 1;
    if (w0 >= Nn) return;
    const bool has1 = (w1 < Nn);
    const int lane = threadIdx.x & 63;
    const int F = VEC * 64;
    const size_t off0 = (size_t)w0 * F + lane * VEC;
    const size_t off1 = (size_t)w1 * F + lane * VEC;

    float acc0[VEC], acc1[VEC];
    if (ADD_SELF) {
        VT v0 = *(const VT*)(cur + off0);
#pragma unroll
        for (int i = 0; i < VEC; i++) acc0[i] = bf2f(v0[i]);
        if (has1) {
            VT v1 = *(const VT*)(cur + off1);
#pragma unroll
            for (int i = 0; i < VEC; i++) acc1[i] = bf2f(v1[i]);
        }
    } else {
#pragma unroll
        for (int i = 0; i < VEC; i++) { acc0[i] = 0.0f; acc1[i] = 0.0f; }
    }
    if (!ADD_SELF) {
#pragma unroll
        for (int i = 0; i < VEC; i++) acc1[i] = 0.0f;
    }

    int e0 = head[w0];
    int e1 = has1 ? head[w1] : -1;

    // interleaved dual-chain walk: both gathers in flight simultaneously
    while (e0 >= 0 && e1 >= 0) {
        int s0 = esrc[e0];
        int s1 = esrc[e1];
        VT v0 = *(const VT*)(cur + (size_t)s0 * F + lane * VEC);
        VT v1 = *(const VT*)(cur + (size_t)s1 * F + lane * VEC);
        e0 = nxt[e0];
        e1 = nxt[e1];
#pragma unroll
        for (int i = 0; i < VEC; i++) { acc0[i] += bf2f(v0[i]); acc1[i] += bf2f(v1[i]); }
    }
    while (e0 >= 0) {
        int s0 = esrc[e0];
        VT v0 = *(const VT*)(cur + (size_t)s0 * F + lane * VEC);
        e0 = nxt[e0];
#pragma unroll
        for (int i = 0; i < VEC; i++) acc0[i] += bf2f(v0[i]);
    }
    while (e1 >= 0) {
        int s1 = esrc[e1];
        VT v1 = *(const VT*)(cur + (size_t)s1 * F + lane * VEC);
        e1 = nxt[e1];
#pragma unroll
        for (int i = 0; i < VEC; i++) acc1[i] += bf2f(v1[i]);
    }

    if (RELU) {
#pragma unroll
        for (int i = 0; i < VEC; i++) {
            if (acc0[i] < 0.0f) acc0[i] = 0.0f;
            if (acc1[i] < 0.0f) acc1[i] = 0.0f;
        }
    }

    if (OUT_F32) {
        float* out = (float*)outp;
        float2 o2;
#pragma unroll
        for (int i = 0; i < VEC; i += 2) {
            o2.x = acc0[i]; o2.y = acc0[i + 1];
            *(float2*)(out + off0 + i) = o2;
        }
        if (has1) {
#pragma unroll
            for (int i = 0; i < VEC; i += 2) {
                o2.x = acc1[i]; o2.y = acc1[i + 1];
                *(float2*)(out + off1 + i) = o2;
            }
        }
    } else {
        VT o0, o1;
#pragma unroll
        for (int i = 0; i < VEC; i++) { o0[i] = f2bf(acc0[i]); o1[i] = f2bf(acc1[i]); }
        if (OUT_STAGED && VEC == 8) {
            *(VT*)((unsigned short*)outp + staged_chunk(w0, lane)) = o0;
            if (has1) *(VT*)((unsigned short*)outp + staged_chunk(w1, lane)) = o1;
        } else {
            *(VT*)((unsigned short*)outp + off0) = o0;
            if (has1) *(VT*)((unsigned short*)outp + off1) = o1;
        }
    }
}

// ---------- launch ----------
extern "C" void kernel_launch(void* const* d_in, const int* in_sizes, int n_in,
                              void* d_out, int out_size, void* d_ws, size_t ws_size,
                              hipStream_t stream)
{
    const float* x  = (const float*)d_in[0];       // [Nn, 512] fp32
    const int*   ei = (const int*)d_in[1];         // [2, E] int32
    const int*   em = (const int*)d_in[2];         // [E]
    const float* W1 = (const float*)d_in[5];       // [512,512]
    const float* b1 = (const float*)d_in[6];       // [512]
    const float* W2 = (const float*)d_in[7];       // [512,128]
    const float* b2 = (const float*)d_in[8];       // [128]

    const int FIN = 512, FOUT = 128;
    const int Nn = in_sizes[0] / FIN;   // 60000
    const int E  = in_sizes[2];         // 160000
    const int Mpad = ((Nn + 127) >> 7) << 7;   // 60032

    char* ws = (char*)d_ws;
    size_t off = 0;
    auto alloc = [&](size_t bytes) -> char* {
        char* p = ws + off;
        off += (bytes + 255) & ~(size_t)255;
        return p;
    };
    unsigned short* W1t = (unsigned short*)alloc((size_t)FIN * FIN * 2);   // staged
    unsigned short* W2t = (unsigned short*)alloc((size_t)FIN * FOUT * 2);  // staged
    unsigned short* xb  = (unsigned short*)alloc((size_t)Mpad * FIN * 2);  // staged x; reused as A1 (linear)
    unsigned short* h1  = (unsigned short*)alloc((size_t)Mpad * FIN * 2);  // GEMM1 out (linear) -> B1 staged
    unsigned short* h2  = (unsigned short*)alloc((size_t)Nn * FOUT * 2);
    unsigned short* A2  = (unsigned short*)alloc((size_t)Nn * FOUT * 2);
    int* head = (int*)alloc((size_t)2 * Nn * 4);   // [2][Nn]
    int* nxt  = (int*)alloc((size_t)E * 4);
    unsigned short* A1 = xb;
    (void)ws_size; (void)n_in; (void)out_size;

    // 1) fused prep (1 launch)
    {
        int nchunk = Nn * (FIN / 8);
        int bc  = (nchunk + 255) / 256;
        int bw1 = (FIN * FIN + 255) / 256;
        int bw2 = (FIN * FOUT + 255) / 256;
        int bh  = (2 * Nn + 255) / 256;
        prep_kernel<<<bc + bw1 + bw2 + bh, 256, 0, stream>>>(
            x, xb, nchunk, bc, W1, W1t, bw1, W2, W2t, bw2, head, 2 * Nn, FIN, FOUT);
    }

    // 2) per-(mask,dst) linked lists
    build_list_kernel<<<(E + 255) / 256, 256, 0, stream>>>(ei, em, E, Nn, head, nxt);

    // 3) h1 = x @ W1 + b1   (staged A/B)
    {
        dim3 grid(FIN / BN, Mpad / BM);
        gemm_bt_bias<<<grid, 256, 0, stream>>>(xb, W1t, b1, h1, Nn, FIN, FIN);
    }

    // props: one wave per NODE PAIR -> grid over (Nn+1)/2 pairs
    const int npair = (Nn + 1) / 2;
    const int pgrid = (npair + 3) / 4;

    // 4) P1: A1 = S0(h1) (linear);  B1 = relu(A1 + S1(A1)) -> STAGED into h1
    {
        prop_step_kernel<8, false, false, false, false><<<pgrid, 256, 0, stream>>>(
            h1, A1, head, nxt, ei, Nn);
        prop_step_kernel<8, true,  true,  false, true ><<<pgrid, 256, 0, stream>>>(
            A1, h1, head + Nn, nxt, ei, Nn);
    }

    // 5) h2 = B1 @ W2 + b2   (staged A/B)
    {
        dim3 grid(FOUT / BN, Mpad / BM);
        gemm_bt_bias<<<grid, 256, 0, stream>>>(h1, W2t, b2, h2, Nn, FOUT, FIN);
    }

    // 6) P2: A2 = S0(h2);  out = A2 + S1(A2)  (fp32)
    {
        prop_step_kernel<2, false, false, false><<<pgrid, 256, 0, stream>>>(
            h2, A2, head, nxt, ei, Nn);
        prop_step_kernel<2, true,  false, true ><<<pgrid, 256, 0, stream>>>(
            A2, d_out, head + Nn, nxt, ei, Nn);
    }
}